// Round 15
// baseline (135.094 us; speedup 1.0000x reference)
//
#include <hip/hip_runtime.h>
#include <math.h>

typedef _Float16 f16x8 __attribute__((ext_vector_type(8)));
typedef float f32x4 __attribute__((ext_vector_type(4)));
typedef unsigned short ushort_t;

#define HW 4096
#define MFMA16 __builtin_amdgcn_mfma_f32_16x16x32_f16

__device__ __forceinline__ ushort_t f2h_u(float v) {
    union { _Float16 h; ushort_t u; } cv; cv.h = (_Float16)v; return cv.u;
}
__device__ __forceinline__ f16x8 splat8(float v) {
    _Float16 h = (_Float16)v;
    f16x8 r;
    #pragma unroll
    for (int i = 0; i < 8; ++i) r[i] = h;
    return r;
}
// LDS-only barrier: wait LDS ops, do NOT drain vmcnt (global prefetch stays
// in flight across the barrier — T4/m201 pattern).
__device__ __forceinline__ void bar_lds() {
    asm volatile("s_waitcnt lgkmcnt(0)" ::: "memory");
    __builtin_amdgcn_s_barrier();
}

// ---------------------------------------------------------------------------
// prep: merged weight-prep + x transpose (R12-proven).
// ---------------------------------------------------------------------------
__global__ __launch_bounds__(256) void prep(
    const float* __restrict__ x, const float* __restrict__ w_dcn,
    const float* __restrict__ w_om,
    ushort_t* __restrict__ w16, ushort_t* __restrict__ wom16,
    ushort_t* __restrict__ xT)
{
    __shared__ ushort_t lds[64 * 256];               // 32 KB (xpose part)
    int tid = threadIdx.x;
    if (blockIdx.x < 2592) {
        int flat = blockIdx.x * 256 + tid;           // 589824 + 73728
        if (flat < 589824) {
            int kk = flat & 31, co = (flat >> 5) & 255, c8 = (flat >> 13) & 7, k = flat >> 16;
            w16[flat] = f2h_u(w_dcn[(size_t)(co * 256 + c8 * 32 + kk) * 9 + k]);
        } else {
            int o = flat - 589824;
            int kk = o & 31, m = (o >> 5) & 31, c8 = (o >> 10) & 7, k = o >> 13;
            float v = (m < 27) ? w_om[(size_t)(m * 256 + c8 * 32 + kk) * 9 + k] : 0.0f;
            wom16[o] = f2h_u(v);
        }
        return;
    }
    int xb_id = blockIdx.x - 2592;                   // 256 blocks
    int b    = xb_id >> 6;
    int pos0 = (xb_id & 63) * 64;
    int posw = tid & 63;
    int ciq  = tid >> 6;                             // 0..3
    const float* xb = x + (size_t)b * 256 * HW + pos0 + posw;
    #pragma unroll
    for (int it = 0; it < 8; ++it) {
        int ci = it * 32 + ciq * 8;
        f16x8 hv;
        #pragma unroll
        for (int j = 0; j < 8; ++j)
            hv[j] = (_Float16)xb[(size_t)(ci + j) * HW];
        int off = posw * 512 + ((ci * 2) ^ ((posw & 7) << 4));
        *(f16x8*)((char*)lds + off) = hv;
    }
    __syncthreads();
    int posr = tid >> 2;
    int cg   = tid & 3;
    char* dst = (char*)(xT + ((size_t)(b * HW) + pos0 + posr) * 256);
    #pragma unroll
    for (int u = 0; u < 8; ++u) {
        int cB = u * 64 + cg * 16;
        f16x8 hv = *(const f16x8*)((const char*)lds + posr * 512 + (cB ^ ((posr & 7) << 4)));
        *(f16x8*)(dst + cB) = hv;
    }
}

// ---------------------------------------------------------------------------
// om_fused: offset-mask conv GEMM + cross-wave reduce + coord transform
// (R12-proven; separate from dcn_fused — merging spills, 3x confirmed).
// ---------------------------------------------------------------------------
__global__ __launch_bounds__(512) void om_fused(
    const ushort_t* __restrict__ xT, const ushort_t* __restrict__ wom16,
    const float* __restrict__ b_om,
    float* __restrict__ py, float* __restrict__ px, float* __restrict__ msk)
{
    int bid = blockIdx.x;                  // 4b*64ho = 256
    int b  = bid >> 6;
    int ho = bid & 63;
    int tid = threadIdx.x;
    int s  = tid >> 6;                     // wave = ci chunk
    int l  = tid & 63;
    int kb = l >> 4, c16 = l & 15;

    __shared__ float sOm[8][2048];         // 64 KB reduce regions

    f32x4 zv = {0.f, 0.f, 0.f, 0.f};
    f32x4 acc[2][4];
    #pragma unroll
    for (int i = 0; i < 2; ++i)
        #pragma unroll
        for (int j = 0; j < 4; ++j) acc[i][j] = zv;
    f16x8 hz;
    #pragma unroll
    for (int j = 0; j < 8; ++j) hz[j] = (_Float16)0.0f;

    const ushort_t* xTb = xT + (size_t)b * HW * 256;

    for (int k9 = 0; k9 < 9; ++k9) {
        int kh = k9 / 3, kw = k9 - kh * 3;
        int y = ho - 1 + kh;
        bool yv = (y >= 0) & (y < 64);
        int yc = min(max(y, 0), 63);
        const ushort_t* wp = wom16 + ((size_t)((k9 * 8 + s) * 32 + c16)) * 32 + kb * 8;
        f16x8 a0 = *(const f16x8*)wp;
        f16x8 a1 = *(const f16x8*)(wp + 512);
        f16x8 bf[4];
        #pragma unroll
        for (int jt = 0; jt < 4; ++jt) {
            int wox = jt * 16 + c16 + kw - 1;
            bool v = yv & (wox >= 0) & (wox < 64);
            int woc = min(max(wox, 0), 63);
            const ushort_t* sp = xTb + ((size_t)(yc * 64 + woc)) * 256 + s * 32 + kb * 8;
            f16x8 bv = *(const f16x8*)sp;
            bf[jt] = v ? bv : hz;
        }
        #pragma unroll
        for (int jt = 0; jt < 4; ++jt) {
            acc[0][jt] = MFMA16(a0, bf[jt], acc[0][jt], 0, 0, 0);
            acc[1][jt] = MFMA16(a1, bf[jt], acc[1][jt], 0, 0, 0);
        }
    }
    #pragma unroll
    for (int i = 0; i < 2; ++i)
        #pragma unroll
        for (int jt = 0; jt < 4; ++jt)
            #pragma unroll
            for (int r = 0; r < 4; ++r)
                sOm[s][(i * 16 + kb * 4 + r) * 64 + jt * 16 + c16] = acc[i][jt][r];
    __syncthreads();

    int e0 = tid * 4;
    int m  = e0 >> 6;                      // 0..31
    int pl = e0 & 63;
    if (m < 27) {
        f32x4 v = zv;
        #pragma unroll
        for (int w8 = 0; w8 < 8; ++w8)
            v += *(const f32x4*)&sOm[w8][e0];
        float bias = b_om[m];
        int pos = ho * 64 + pl;
        if (m < 9) {
            int kh = m / 3;
            float* o = py + (size_t)(b * 9 + m) * HW + pos;
            #pragma unroll
            for (int j = 0; j < 4; ++j)
                o[j] = (float)(ho - 1 + kh) + v[j] + bias;
        } else if (m < 18) {
            int k = m - 9, kw = k % 3;
            float* o = px + (size_t)(b * 9 + k) * HW + pos;
            #pragma unroll
            for (int j = 0; j < 4; ++j)
                o[j] = (float)(pl + j - 1 + kw) + v[j] + bias;
        } else {
            int k = m - 18;
            float* o = msk + (size_t)(b * 9 + k) * HW + pos;
            #pragma unroll
            for (int j = 0; j < 4; ++j)
                o[j] = 1.0f / (1.0f + expf(-(v[j] + bias)));
        }
    }
}

// ---------------------------------------------------------------------------
// dcn_fused: R12 structure. CHANGES vs R12 (both phase-2-local):
//  (1) UPD split into UPD_LOAD (coord global loads issued one loop iteration
//      ~2 barriers ahead) + UPD_CALC (consume) — removes the ~9x/half fully
//      serialized coord-load -> gather-address dependency.
//  (2) s_setprio(1) around the MFMA cluster (T5; phase-split loop).
// ---------------------------------------------------------------------------
__global__ __launch_bounds__(1024, 1) void dcn_fused(
    const ushort_t* __restrict__ xT, const ushort_t* __restrict__ w16,
    const float* __restrict__ b_dcn,
    const float* __restrict__ py, const float* __restrict__ px,
    const float* __restrict__ msk, float* __restrict__ out)
{
    int bid  = blockIdx.x;                 // 4b * 64pt
    int b    = bid >> 6;
    int pos0 = (bid & 63) * 64;
    int tid  = threadIdx.x;
    int h    = tid >> 9;                   // K-half
    int t5   = tid & 511;
    int w    = t5 >> 6, l = t5 & 63;
    int kb   = l >> 4, c16 = l & 15;
    int g8   = t5 & 7, spos = t5 >> 3;     // sampler decomposition (g8 fastest)
    int c0   = h * 18;                     // first chunk of this half

    __shared__ __align__(16) ushort_t sB2[2][2][4096];  // [half][buf] 32 KB
    __shared__ float sR[512 * 33];                      // 67.6 KB reduce

    ushort_t (&sB)[2][4096] = sB2[h];

    const ushort_t* xTb   = xT + (size_t)b * HW * 256;
    const ushort_t* wbase = w16 + (size_t)(w * 32 + c16) * 32 + kb * 8;

    f32x4 zv = {0.f, 0.f, 0.f, 0.f};
    f32x4 acc[2][4];
    #pragma unroll
    for (int i = 0; i < 2; ++i)
        #pragma unroll
        for (int j = 0; j < 4; ++j) acc[i][j] = zv;

    int o00 = 0, o01 = 0, o10 = 0, o11 = 0;
    float tw00 = 0.f, tw01 = 0.f, tw10 = 0.f, tw11 = 0.f;
    float fyN = 0.f, fxN = 0.f, mvN = 0.f;      // prefetched coords
    f32x4 wA, wB;
    f16x8 gA00, gA01, gA10, gA11;
    f16x8 gB00, gB01, gB10, gB11;
    f16x8 aA00, aA01, aA10, aA11;
    f16x8 aB00, aB01, aB10, aB11;

    // issue the 3 coord loads for tap K9 (results land in fyN/fxN/mvN)
#define UPD_LOAD(K9)                                                          \
    do {                                                                      \
        size_t gidx = (size_t)(b * 9 + (K9)) * HW + pos0 + spos;              \
        fyN = py[gidx]; fxN = px[gidx]; mvN = msk[gidx];                      \
    } while (0)

    // consume prefetched coords -> corner offsets + weights
#define UPD_CALC()                                                            \
    do {                                                                      \
        float fy = fyN, fx = fxN, mv = mvN;                                   \
        float y0f = floorf(fy), x0f = floorf(fx);                             \
        int y0 = (int)y0f, x0 = (int)x0f;                                     \
        float dy = fy - y0f, dx = fx - x0f;                                   \
        bool vy0 = (y0 >= 0) & (y0 < 64);                                     \
        bool vy1 = (y0 >= -1) & (y0 < 63);                                    \
        bool vx0 = (x0 >= 0) & (x0 < 64);                                     \
        bool vx1 = (x0 >= -1) & (x0 < 63);                                    \
        int y0c = min(max(y0, 0), 63), y1c = min(max(y0 + 1, 0), 63);         \
        int x0c = min(max(x0, 0), 63), x1c = min(max(x0 + 1, 0), 63);         \
        o00 = (y0c * 64 + x0c) * 256; o01 = (y0c * 64 + x1c) * 256;           \
        o10 = (y1c * 64 + x0c) * 256; o11 = (y1c * 64 + x1c) * 256;           \
        tw00 = (vy0 && vx0) ? (1.f - dy) * (1.f - dx) * mv : 0.f;             \
        tw01 = (vy0 && vx1) ? (1.f - dy) * dx * mv : 0.f;                     \
        tw10 = (vy1 && vx0) ? dy * (1.f - dx) * mv : 0.f;                     \
        tw11 = (vy1 && vx1) ? dy * dx * mv : 0.f;                             \
    } while (0)

#define ISS(S, CHUNK)                                                         \
    do {                                                                      \
        int cio = ((CHUNK) & 3) * 64 + g8 * 8;                                \
        g##S##00 = *(const f16x8*)(xTb + o00 + cio);                          \
        g##S##01 = *(const f16x8*)(xTb + o01 + cio);                          \
        g##S##10 = *(const f16x8*)(xTb + o10 + cio);                          \
        g##S##11 = *(const f16x8*)(xTb + o11 + cio);                          \
        w##S[0] = tw00; w##S[1] = tw01; w##S[2] = tw10; w##S[3] = tw11;       \
    } while (0)

#define CMB(S, CHUNK)                                                         \
    do {                                                                      \
        f16x8 s00 = splat8(w##S[0]), s01 = splat8(w##S[1]);                   \
        f16x8 s10 = splat8(w##S[2]), s11 = splat8(w##S[3]);                   \
        f16x8 res = g##S##00 * s00 + g##S##01 * s01                           \
                  + g##S##10 * s10 + g##S##11 * s11;                          \
        int byo = (g8 * 1024 + spos * 16) ^ (g8 << 4);                        \
        *(f16x8*)((char*)&sB[(CHUNK) & 1][0] + byo) = res;                    \
    } while (0)

#define LOADA(S, IT)                                                          \
    do {                                                                      \
        const ushort_t* ap = wbase + (size_t)(IT) * 16384;                    \
        a##S##00 = *(const f16x8*)ap;                                         \
        a##S##01 = *(const f16x8*)(ap + 512);                                 \
        a##S##10 = *(const f16x8*)(ap + 8192);                                \
        a##S##11 = *(const f16x8*)(ap + 8192 + 512);                          \
    } while (0)

#define MFMACORE(IT, S)                                                       \
    do {                                                                      \
        const char* bb = (const char*)&sB[(IT) & 1][0];                       \
        f16x8 b0[4], b1[4];                                                   \
        _Pragma("unroll")                                                     \
        for (int jt = 0; jt < 4; ++jt) {                                      \
            int p16 = (jt * 16 + c16) * 16;                                   \
            b0[jt] = *(const f16x8*)(bb + ((kb * 1024 + p16) ^ (kb << 4)));   \
            b1[jt] = *(const f16x8*)(bb + (((kb + 4) * 1024 + p16) ^ ((kb + 4) << 4))); \
        }                                                                     \
        __builtin_amdgcn_s_setprio(1);                                        \
        _Pragma("unroll")                                                     \
        for (int jt = 0; jt < 4; ++jt) {                                      \
            acc[0][jt] = MFMA16(a##S##00, b0[jt], acc[0][jt], 0, 0, 0);       \
            acc[1][jt] = MFMA16(a##S##01, b0[jt], acc[1][jt], 0, 0, 0);       \
        }                                                                     \
        _Pragma("unroll")                                                     \
        for (int jt = 0; jt < 4; ++jt) {                                      \
            acc[0][jt] = MFMA16(a##S##10, b1[jt], acc[0][jt], 0, 0, 0);       \
            acc[1][jt] = MFMA16(a##S##11, b1[jt], acc[1][jt], 0, 0, 0);       \
        }                                                                     \
        __builtin_amdgcn_s_setprio(0);                                        \
    } while (0)

    // ---- prologue: coords for first tap (+next tap if mid-group start) ----
    UPD_LOAD(c0 >> 2);
    UPD_CALC();
    ISS(A, c0);
    ISS(B, c0 + 1);
    LOADA(A, c0);
    if ((c0 & 3) == 2) UPD_LOAD((c0 + 2) >> 2);   // half 1: pre-load tap 5
    CMB(A, c0);
    bar_lds();

    // ---- main loop: 2 chunks/iter. Coord loads issued 1 iter ahead of
    //      their UPD_CALC (base&3==0 -> load tap (base+4)>>2;
    //      base&3==2 -> calc tap (base+2)>>2). ----
    for (int base = c0; base < c0 + 16; base += 2) {
        LOADA(B, base + 1);
        if ((base & 3) == 0) {
            int t9 = (base + 4) >> 2;
            if (t9 <= 8) UPD_LOAD(t9);
        } else {
            UPD_CALC();
        }
        ISS(A, base + 2);
        CMB(B, base + 1);
        MFMACORE(base, A);
        bar_lds();
        LOADA(A, base + 2);
        ISS(B, base + 3);
        CMB(A, base + 2);
        MFMACORE(base + 1, B);
        bar_lds();
    }
    // tail: chunks c0+16, c0+17
    LOADA(B, c0 + 17);
    CMB(B, c0 + 17);
    MFMACORE(c0 + 16, A);
    bar_lds();
    MFMACORE(c0 + 17, B);

#undef UPD_LOAD
#undef UPD_CALC
#undef ISS
#undef CMB
#undef LOADA
#undef MFMACORE

    // ---- cross-half reduce (stride 33 -> conflict-free), then epilogue ----
    __syncthreads();
    if (h == 1) {
        #pragma unroll
        for (int i = 0; i < 2; ++i)
            #pragma unroll
            for (int jt = 0; jt < 4; ++jt)
                #pragma unroll
                for (int r = 0; r < 4; ++r)
                    sR[t5 * 33 + (i * 4 + jt) * 4 + r] = acc[i][jt][r];
    }
    __syncthreads();
    if (h == 0) {
        #pragma unroll
        for (int i = 0; i < 2; ++i)
            #pragma unroll
            for (int jt = 0; jt < 4; ++jt)
                #pragma unroll
                for (int r = 0; r < 4; ++r)
                    acc[i][jt][r] += sR[t5 * 33 + (i * 4 + jt) * 4 + r];
        #pragma unroll
        for (int i = 0; i < 2; ++i)
            #pragma unroll
            for (int r = 0; r < 4; ++r) {
                int co = w * 32 + i * 16 + kb * 4 + r;
                float bias = b_dcn[co];
                float* orow = out + (size_t)(b * 256 + co) * HW + pos0;
                #pragma unroll
                for (int jt = 0; jt < 4; ++jt)
                    orow[jt * 16 + c16] = fmaxf(acc[i][jt][r] + bias, 0.f);
            }
    }
}

// ---------------------------------------------------------------------------
extern "C" void kernel_launch(void* const* d_in, const int* in_sizes, int n_in,
                              void* d_out, int out_size, void* d_ws, size_t ws_size,
                              hipStream_t stream) {
    const float* x     = (const float*)d_in[0];
    const float* w_om  = (const float*)d_in[1];
    const float* b_om  = (const float*)d_in[2];
    const float* w_dcn = (const float*)d_in[3];
    const float* b_dcn = (const float*)d_in[4];
    float* out = (float*)d_out;

    float* ws = (float*)d_ws;
    // float-offsets (total ~11.5 MB)
    float* py   = ws;                              // 147456
    float* px   = ws + 147456;
    float* msk  = ws + 294912;
    ushort_t* w16   = (ushort_t*)(ws + 442368);    // 589824 f16
    ushort_t* wom16 = (ushort_t*)(ws + 737280);    // 73728 f16
    ushort_t* xT    = (ushort_t*)(ws + 774144);    // 4,194,304 f16

    prep     <<<2848, 256,  0, stream>>>(x, w_dcn, w_om, w16, wom16, xT);
    om_fused <<<256,  512,  0, stream>>>(xT, wom16, b_om, py, px, msk);
    dcn_fused<<<256,  1024, 0, stream>>>(xT, w16, b_dcn, py, px, msk, out);
}

// Round 16
// 59.936 us; speedup vs baseline: 2.2540x; 2.2540x over previous
//
#include <hip/hip_runtime.h>
#include <math.h>

typedef _Float16 f16x8 __attribute__((ext_vector_type(8)));
typedef float f32x4 __attribute__((ext_vector_type(4)));
typedef unsigned short ushort_t;

#define HW 4096
#define MFMA16 __builtin_amdgcn_mfma_f32_16x16x32_f16

__device__ __forceinline__ ushort_t f2h_u(float v) {
    union { _Float16 h; ushort_t u; } cv; cv.h = (_Float16)v; return cv.u;
}
__device__ __forceinline__ f16x8 splat8(float v) {
    _Float16 h = (_Float16)v;
    f16x8 r;
    #pragma unroll
    for (int i = 0; i < 8; ++i) r[i] = h;
    return r;
}
// LDS-only barrier: wait LDS ops, do NOT drain vmcnt (global prefetch stays
// in flight across the barrier — T4/m201 pattern).
__device__ __forceinline__ void bar_lds() {
    asm volatile("s_waitcnt lgkmcnt(0)" ::: "memory");
    __builtin_amdgcn_s_barrier();
}

// ---------------------------------------------------------------------------
// prep: merged weight-prep + x transpose (independent work, one launch).
//  blocks [0,2592):  w16  [9][8][256co][32kk] = w_dcn[co][c8*32+kk][k]
//                    wom16[9][8][32m ][32kk]  = w_om[m][c8*32+kk][k] (m>=27->0)
//  blocks [2592,2848): xT f16 [b][pos][ci]  (LDS-tiled transpose of x)
// ---------------------------------------------------------------------------
__global__ __launch_bounds__(256) void prep(
    const float* __restrict__ x, const float* __restrict__ w_dcn,
    const float* __restrict__ w_om,
    ushort_t* __restrict__ w16, ushort_t* __restrict__ wom16,
    ushort_t* __restrict__ xT)
{
    __shared__ ushort_t lds[64 * 256];               // 32 KB (xpose part)
    int tid = threadIdx.x;
    if (blockIdx.x < 2592) {
        int flat = blockIdx.x * 256 + tid;           // 589824 + 73728
        if (flat < 589824) {
            int kk = flat & 31, co = (flat >> 5) & 255, c8 = (flat >> 13) & 7, k = flat >> 16;
            w16[flat] = f2h_u(w_dcn[(size_t)(co * 256 + c8 * 32 + kk) * 9 + k]);
        } else {
            int o = flat - 589824;
            int kk = o & 31, m = (o >> 5) & 31, c8 = (o >> 10) & 7, k = o >> 13;
            float v = (m < 27) ? w_om[(size_t)(m * 256 + c8 * 32 + kk) * 9 + k] : 0.0f;
            wom16[o] = f2h_u(v);
        }
        return;
    }
    int xb_id = blockIdx.x - 2592;                   // 256 blocks
    int b    = xb_id >> 6;
    int pos0 = (xb_id & 63) * 64;
    int posw = tid & 63;
    int ciq  = tid >> 6;                             // 0..3
    const float* xb = x + (size_t)b * 256 * HW + pos0 + posw;
    #pragma unroll
    for (int it = 0; it < 8; ++it) {
        int ci = it * 32 + ciq * 8;
        f16x8 hv;
        #pragma unroll
        for (int j = 0; j < 8; ++j)
            hv[j] = (_Float16)xb[(size_t)(ci + j) * HW];
        int off = posw * 512 + ((ci * 2) ^ ((posw & 7) << 4));
        *(f16x8*)((char*)lds + off) = hv;
    }
    __syncthreads();
    int posr = tid >> 2;
    int cg   = tid & 3;
    char* dst = (char*)(xT + ((size_t)(b * HW) + pos0 + posr) * 256);
    #pragma unroll
    for (int u = 0; u < 8; ++u) {
        int cB = u * 64 + cg * 16;
        f16x8 hv = *(const f16x8*)((const char*)lds + posr * 512 + (cB ^ ((posr & 7) << 4)));
        *(f16x8*)(dst + cB) = hv;
    }
}

// ---------------------------------------------------------------------------
// om_fused: offset-mask conv GEMM + cross-wave reduce + coord transform.
// Block = (b,ho): 8 waves, wave s handles ci s*32..s*32+31 over all 9 taps
// (32m x 64pos tile each). LDS tree-reduce (8 regions), then 512 threads
// sum + bias + transform -> py/px/sigmoid(mask). No part buffer.
// ---------------------------------------------------------------------------
__global__ __launch_bounds__(512) void om_fused(
    const ushort_t* __restrict__ xT, const ushort_t* __restrict__ wom16,
    const float* __restrict__ b_om,
    float* __restrict__ py, float* __restrict__ px, float* __restrict__ msk)
{
    int bid = blockIdx.x;                  // 4b*64ho = 256
    int b  = bid >> 6;
    int ho = bid & 63;
    int tid = threadIdx.x;
    int s  = tid >> 6;                     // wave = ci chunk
    int l  = tid & 63;
    int kb = l >> 4, c16 = l & 15;

    __shared__ float sOm[8][2048];         // 64 KB reduce regions

    f32x4 zv = {0.f, 0.f, 0.f, 0.f};
    f32x4 acc[2][4];
    #pragma unroll
    for (int i = 0; i < 2; ++i)
        #pragma unroll
        for (int j = 0; j < 4; ++j) acc[i][j] = zv;
    f16x8 hz;
    #pragma unroll
    for (int j = 0; j < 8; ++j) hz[j] = (_Float16)0.0f;

    const ushort_t* xTb = xT + (size_t)b * HW * 256;

    for (int k9 = 0; k9 < 9; ++k9) {
        int kh = k9 / 3, kw = k9 - kh * 3;
        int y = ho - 1 + kh;
        bool yv = (y >= 0) & (y < 64);
        int yc = min(max(y, 0), 63);
        const ushort_t* wp = wom16 + ((size_t)((k9 * 8 + s) * 32 + c16)) * 32 + kb * 8;
        f16x8 a0 = *(const f16x8*)wp;
        f16x8 a1 = *(const f16x8*)(wp + 512);
        f16x8 bf[4];
        #pragma unroll
        for (int jt = 0; jt < 4; ++jt) {
            int wox = jt * 16 + c16 + kw - 1;
            bool v = yv & (wox >= 0) & (wox < 64);
            int woc = min(max(wox, 0), 63);
            const ushort_t* sp = xTb + ((size_t)(yc * 64 + woc)) * 256 + s * 32 + kb * 8;
            f16x8 bv = *(const f16x8*)sp;
            bf[jt] = v ? bv : hz;
        }
        #pragma unroll
        for (int jt = 0; jt < 4; ++jt) {
            acc[0][jt] = MFMA16(a0, bf[jt], acc[0][jt], 0, 0, 0);
            acc[1][jt] = MFMA16(a1, bf[jt], acc[1][jt], 0, 0, 0);
        }
    }
    // write region s
    #pragma unroll
    for (int i = 0; i < 2; ++i)
        #pragma unroll
        for (int jt = 0; jt < 4; ++jt)
            #pragma unroll
            for (int r = 0; r < 4; ++r)
                sOm[s][(i * 16 + kb * 4 + r) * 64 + jt * 16 + c16] = acc[i][jt][r];
    __syncthreads();

    // 512 threads x 4 consecutive pos each
    int e0 = tid * 4;
    int m  = e0 >> 6;                      // 0..31
    int pl = e0 & 63;                      // 0,4,..,60
    if (m < 27) {
        f32x4 v = zv;
        #pragma unroll
        for (int w8 = 0; w8 < 8; ++w8)
            v += *(const f32x4*)&sOm[w8][e0];
        float bias = b_om[m];
        int pos = ho * 64 + pl;
        if (m < 9) {
            int kh = m / 3;
            float* o = py + (size_t)(b * 9 + m) * HW + pos;
            #pragma unroll
            for (int j = 0; j < 4; ++j)
                o[j] = (float)(ho - 1 + kh) + v[j] + bias;
        } else if (m < 18) {
            int k = m - 9, kw = k % 3;
            float* o = px + (size_t)(b * 9 + k) * HW + pos;
            #pragma unroll
            for (int j = 0; j < 4; ++j)
                o[j] = (float)(pl + j - 1 + kw) + v[j] + bias;
        } else {
            int k = m - 18;
            float* o = msk + (size_t)(b * 9 + k) * HW + pos;
            #pragma unroll
            for (int j = 0; j < 4; ++j)
                o[j] = 1.0f / (1.0f + expf(-(v[j] + bias)));
        }
    }
}

// ---------------------------------------------------------------------------
// dcn_fused: bilinear sample + masked im2col + MFMA GEMM + bias + ReLU.
// 1024 threads = 16 waves = 2 K-halves x 8 waves. Half h does chunks
// [h*18, h*18+18) with its own LDS double-buffer. Grid = 256 (1 block/CU,
// pinned by 135 KB LDS). Depth-2 register pipeline for gathers AND
// A-weights; LDS-only barriers (vmcnt never drained in loop). Cross-half
// reduce in LDS, epilogue by half 0.
// DO NOT add live state or scheduling intrinsics to the phase-2 loop:
// R9/R10/R14/R15 each tipped the register allocator into a 64-VGPR +
// ~200 MB scratch-spill mode (2x regression). This exact formulation is
// proven just under that cliff (59.94 us total).
// ---------------------------------------------------------------------------
__global__ __launch_bounds__(1024, 1) void dcn_fused(
    const ushort_t* __restrict__ xT, const ushort_t* __restrict__ w16,
    const float* __restrict__ b_dcn,
    const float* __restrict__ py, const float* __restrict__ px,
    const float* __restrict__ msk, float* __restrict__ out)
{
    int bid  = blockIdx.x;                 // 4b * 64pt
    int b    = bid >> 6;
    int pos0 = (bid & 63) * 64;
    int tid  = threadIdx.x;
    int h    = tid >> 9;                   // K-half
    int t5   = tid & 511;
    int w    = t5 >> 6, l = t5 & 63;
    int kb   = l >> 4, c16 = l & 15;
    int g8   = t5 & 7, spos = t5 >> 3;     // sampler decomposition (g8 fastest)
    int c0   = h * 18;                     // first chunk of this half

    __shared__ __align__(16) ushort_t sB2[2][2][4096];  // [half][buf] 32 KB
    __shared__ float sR[512 * 33];                      // 67.6 KB reduce

    ushort_t (&sB)[2][4096] = sB2[h];

    const ushort_t* xTb   = xT + (size_t)b * HW * 256;
    const ushort_t* wbase = w16 + (size_t)(w * 32 + c16) * 32 + kb * 8;

    f32x4 zv = {0.f, 0.f, 0.f, 0.f};
    f32x4 acc[2][4];
    #pragma unroll
    for (int i = 0; i < 2; ++i)
        #pragma unroll
        for (int j = 0; j < 4; ++j) acc[i][j] = zv;

    int o00 = 0, o01 = 0, o10 = 0, o11 = 0;
    float tw00 = 0.f, tw01 = 0.f, tw10 = 0.f, tw11 = 0.f;
    f32x4 wA, wB;
    f16x8 gA00, gA01, gA10, gA11;
    f16x8 gB00, gB01, gB10, gB11;
    f16x8 aA00, aA01, aA10, aA11;
    f16x8 aB00, aB01, aB10, aB11;

#define UPD(K9)                                                               \
    do {                                                                      \
        size_t gidx = (size_t)(b * 9 + (K9)) * HW + pos0 + spos;              \
        float fy = py[gidx], fx = px[gidx], mv = msk[gidx];                   \
        float y0f = floorf(fy), x0f = floorf(fx);                             \
        int y0 = (int)y0f, x0 = (int)x0f;                                     \
        float dy = fy - y0f, dx = fx - x0f;                                   \
        bool vy0 = (y0 >= 0) & (y0 < 64);                                     \
        bool vy1 = (y0 >= -1) & (y0 < 63);                                    \
        bool vx0 = (x0 >= 0) & (x0 < 64);                                     \
        bool vx1 = (x0 >= -1) & (x0 < 63);                                    \
        int y0c = min(max(y0, 0), 63), y1c = min(max(y0 + 1, 0), 63);         \
        int x0c = min(max(x0, 0), 63), x1c = min(max(x0 + 1, 0), 63);         \
        o00 = (y0c * 64 + x0c) * 256; o01 = (y0c * 64 + x1c) * 256;           \
        o10 = (y1c * 64 + x0c) * 256; o11 = (y1c * 64 + x1c) * 256;           \
        tw00 = (vy0 && vx0) ? (1.f - dy) * (1.f - dx) * mv : 0.f;             \
        tw01 = (vy0 && vx1) ? (1.f - dy) * dx * mv : 0.f;                     \
        tw10 = (vy1 && vx0) ? dy * (1.f - dx) * mv : 0.f;                     \
        tw11 = (vy1 && vx1) ? dy * dx * mv : 0.f;                             \
    } while (0)

#define ISS(S, CHUNK)                                                         \
    do {                                                                      \
        int cio = ((CHUNK) & 3) * 64 + g8 * 8;                                \
        g##S##00 = *(const f16x8*)(xTb + o00 + cio);                          \
        g##S##01 = *(const f16x8*)(xTb + o01 + cio);                          \
        g##S##10 = *(const f16x8*)(xTb + o10 + cio);                          \
        g##S##11 = *(const f16x8*)(xTb + o11 + cio);                          \
        w##S[0] = tw00; w##S[1] = tw01; w##S[2] = tw10; w##S[3] = tw11;       \
    } while (0)

#define CMB(S, CHUNK)                                                         \
    do {                                                                      \
        f16x8 s00 = splat8(w##S[0]), s01 = splat8(w##S[1]);                   \
        f16x8 s10 = splat8(w##S[2]), s11 = splat8(w##S[3]);                   \
        f16x8 res = g##S##00 * s00 + g##S##01 * s01                           \
                  + g##S##10 * s10 + g##S##11 * s11;                          \
        int byo = (g8 * 1024 + spos * 16) ^ (g8 << 4);                        \
        *(f16x8*)((char*)&sB[(CHUNK) & 1][0] + byo) = res;                    \
    } while (0)

#define LOADA(S, IT)                                                          \
    do {                                                                      \
        const ushort_t* ap = wbase + (size_t)(IT) * 16384;                    \
        a##S##00 = *(const f16x8*)ap;                                         \
        a##S##01 = *(const f16x8*)(ap + 512);                                 \
        a##S##10 = *(const f16x8*)(ap + 8192);                                \
        a##S##11 = *(const f16x8*)(ap + 8192 + 512);                          \
    } while (0)

#define MFMACORE(IT, S)                                                       \
    do {                                                                      \
        const char* bb = (const char*)&sB[(IT) & 1][0];                       \
        f16x8 b0[4], b1[4];                                                   \
        _Pragma("unroll")                                                     \
        for (int jt = 0; jt < 4; ++jt) {                                      \
            int p16 = (jt * 16 + c16) * 16;                                   \
            b0[jt] = *(const f16x8*)(bb + ((kb * 1024 + p16) ^ (kb << 4)));   \
            b1[jt] = *(const f16x8*)(bb + (((kb + 4) * 1024 + p16) ^ ((kb + 4) << 4))); \
        }                                                                     \
        _Pragma("unroll")                                                     \
        for (int jt = 0; jt < 4; ++jt) {                                      \
            acc[0][jt] = MFMA16(a##S##00, b0[jt], acc[0][jt], 0, 0, 0);       \
            acc[1][jt] = MFMA16(a##S##01, b0[jt], acc[1][jt], 0, 0, 0);       \
        }                                                                     \
        _Pragma("unroll")                                                     \
        for (int jt = 0; jt < 4; ++jt) {                                      \
            acc[0][jt] = MFMA16(a##S##10, b1[jt], acc[0][jt], 0, 0, 0);       \
            acc[1][jt] = MFMA16(a##S##11, b1[jt], acc[1][jt], 0, 0, 0);       \
        }                                                                     \
    } while (0)

    // ---- prologue: coords for this half's first tap; stage first chunk ----
    UPD(c0 >> 2);
    ISS(A, c0);
    ISS(B, c0 + 1);
    LOADA(A, c0);
    CMB(A, c0);
    bar_lds();

    // ---- main loop: 2 chunks/iter (even chunk -> set A, odd -> set B) ----
    for (int base = c0; base < c0 + 16; base += 2) {
        LOADA(B, base + 1);
        if (((base + 2) & 3) == 0) UPD((base + 2) >> 2);
        ISS(A, base + 2);
        CMB(B, base + 1);
        MFMACORE(base, A);
        bar_lds();
        LOADA(A, base + 2);
        ISS(B, base + 3);
        CMB(A, base + 2);
        MFMACORE(base + 1, B);
        bar_lds();
    }
    // tail: chunks c0+16, c0+17
    LOADA(B, c0 + 17);
    CMB(B, c0 + 17);
    MFMACORE(c0 + 16, A);
    bar_lds();
    MFMACORE(c0 + 17, B);

#undef UPD
#undef ISS
#undef CMB
#undef LOADA
#undef MFMACORE

    // ---- cross-half reduce (stride 33 -> conflict-free), then epilogue ----
    __syncthreads();
    if (h == 1) {
        #pragma unroll
        for (int i = 0; i < 2; ++i)
            #pragma unroll
            for (int jt = 0; jt < 4; ++jt)
                #pragma unroll
                for (int r = 0; r < 4; ++r)
                    sR[t5 * 33 + (i * 4 + jt) * 4 + r] = acc[i][jt][r];
    }
    __syncthreads();
    if (h == 0) {
        #pragma unroll
        for (int i = 0; i < 2; ++i)
            #pragma unroll
            for (int jt = 0; jt < 4; ++jt)
                #pragma unroll
                for (int r = 0; r < 4; ++r)
                    acc[i][jt][r] += sR[t5 * 33 + (i * 4 + jt) * 4 + r];
        #pragma unroll
        for (int i = 0; i < 2; ++i)
            #pragma unroll
            for (int r = 0; r < 4; ++r) {
                int co = w * 32 + i * 16 + kb * 4 + r;
                float bias = b_dcn[co];
                float* orow = out + (size_t)(b * 256 + co) * HW + pos0;
                #pragma unroll
                for (int jt = 0; jt < 4; ++jt)
                    orow[jt * 16 + c16] = fmaxf(acc[i][jt][r] + bias, 0.f);
            }
    }
}

// ---------------------------------------------------------------------------
extern "C" void kernel_launch(void* const* d_in, const int* in_sizes, int n_in,
                              void* d_out, int out_size, void* d_ws, size_t ws_size,
                              hipStream_t stream) {
    const float* x     = (const float*)d_in[0];
    const float* w_om  = (const float*)d_in[1];
    const float* b_om  = (const float*)d_in[2];
    const float* w_dcn = (const float*)d_in[3];
    const float* b_dcn = (const float*)d_in[4];
    float* out = (float*)d_out;

    float* ws = (float*)d_ws;
    // float-offsets (total ~11.5 MB)
    float* py   = ws;                              // 147456
    float* px   = ws + 147456;
    float* msk  = ws + 294912;
    ushort_t* w16   = (ushort_t*)(ws + 442368);    // 589824 f16
    ushort_t* wom16 = (ushort_t*)(ws + 737280);    // 73728 f16
    ushort_t* xT    = (ushort_t*)(ws + 774144);    // 4,194,304 f16

    prep     <<<2848, 256,  0, stream>>>(x, w_dcn, w_om, w16, wom16, xT);
    om_fused <<<256,  512,  0, stream>>>(xT, wom16, b_om, py, px, msk);
    dcn_fused<<<256,  1024, 0, stream>>>(xT, w16, b_dcn, py, px, msk, out);
}